// Round 2
// baseline (283.321 us; speedup 1.0000x reference)
//
#include <hip/hip_runtime.h>
#include <hip/hip_bf16.h>
#include <math.h>

// Problem constants (fixed by setup_inputs)
#define B_    16
#define CIN   512
#define SEQ   1024
#define NH    4
#define DK    128
#define OUT3  1536
#define SCALE 0.08838834764831845f   // 1/sqrt(128)

typedef __attribute__((ext_vector_type(8))) __bf16 bf16x8;   // MFMA A/B frag (4 VGPR)
typedef __attribute__((ext_vector_type(4))) float f32x4;     // MFMA C/D frag

#define MFMA(a, b, c) __builtin_amdgcn_mfma_f32_16x16x32_bf16((a), (b), (c), 0, 0, 0)

__device__ __forceinline__ ushort f2bf(float f) {
    __hip_bfloat16 h = __float2bfloat16(f);   // RTNE
    return *(ushort*)&h;
}
__device__ __forceinline__ uint pk2(float a, float b) {
    return (uint)f2bf(a) | ((uint)f2bf(b) << 16);
}

// ---------------------------------------------------------------------------
// k0: x [B][C][seq] fp32  ->  xt [B][seq][C] bf16   (LDS transpose, 64x64 tile)
// ---------------------------------------------------------------------------
__global__ __launch_bounds__(256) void transpose_cast_kernel(
    const float* __restrict__ x, ushort* __restrict__ xt)
{
    __shared__ ushort t[64 * 66];   // [c][i], stride 66 => 2-way max on writes
    const int tid = threadIdx.x;
    const int i0 = blockIdx.x * 64, c0 = blockIdx.y * 64, b = blockIdx.z;

    #pragma unroll
    for (int l = 0; l < 4; ++l) {
        int idx = tid + l * 256;               // 0..1023
        int c = idx >> 4, i4 = (idx & 15) << 2;
        float4 v = *(const float4*)&x[((size_t)b * CIN + c0 + c) * SEQ + i0 + i4];
        t[(i4 + 0) * 66 + c] = f2bf(v.x);
        t[(i4 + 1) * 66 + c] = f2bf(v.y);
        t[(i4 + 2) * 66 + c] = f2bf(v.z);
        t[(i4 + 3) * 66 + c] = f2bf(v.w);
    }
    __syncthreads();
    #pragma unroll
    for (int l = 0; l < 4; ++l) {
        int idx = tid + l * 256;
        int i = idx >> 4, c4 = (idx & 15) << 2;
        uint2 p;
        p.x = *(const uint*)&t[i * 66 + c4];
        p.y = *(const uint*)&t[i * 66 + c4 + 2];
        *(uint2*)&xt[((size_t)b * SEQ + i0 + i) * CIN + c0 + c4] = p;
    }
}

// ---------------------------------------------------------------------------
// k1: QKV projection.  D[o][i] = sum_c W[o][c] * xt[i][c]  (+bias)
// Block: 128 o x 128 i, 4 waves (2x2), wave 64x64, BK=32.
// q,k -> [bh][seq][128] bf16 ; v -> TRANSPOSED [bh][128][seq] bf16.
// ---------------------------------------------------------------------------
__global__ __launch_bounds__(256) void qkv_kernel(
    const float* __restrict__ w, const float* __restrict__ bias,
    const ushort* __restrict__ xt,
    ushort* __restrict__ qb, ushort* __restrict__ kb, ushort* __restrict__ vtb)
{
    __shared__ ushort lds_w[128 * 40];   // [o][c]  (stride 40 => 80B, 2-way max)
    __shared__ ushort lds_x[128 * 40];   // [i][c]
    const int tid = threadIdx.x;
    const int lane = tid & 63, wv = tid >> 6;
    const int l15 = lane & 15, l4 = lane >> 4;
    const int wm = wv >> 1, wn = wv & 1;
    const int o0 = blockIdx.x * 128, i0 = blockIdx.y * 128, b = blockIdx.z;

    f32x4 acc[4][4] = {};   // [o-sub][i-sub]
    for (int c0 = 0; c0 < CIN; c0 += 32) {
        __syncthreads();
        #pragma unroll
        for (int l = 0; l < 4; ++l) {            // W tile: fp32 -> bf16
            int idx = tid + l * 256;             // 1024 float4-quads
            int o = idx >> 3, cq = (idx & 7) << 2;
            float4 v = *(const float4*)&w[(size_t)(o0 + o) * CIN + c0 + cq];
            uint2 p; p.x = pk2(v.x, v.y); p.y = pk2(v.z, v.w);
            *(uint2*)&lds_w[o * 40 + cq] = p;
        }
        #pragma unroll
        for (int l = 0; l < 2; ++l) {            // xt tile: bf16 copy 16B
            int idx = tid + l * 256;             // 512 16B chunks
            int i = idx >> 2, cq = (idx & 3) << 3;
            *(uint4*)&lds_x[i * 40 + cq] =
                *(const uint4*)&xt[((size_t)b * SEQ + i0 + i) * CIN + c0 + cq];
        }
        __syncthreads();
        bf16x8 af[4], bfr[4];
        #pragma unroll
        for (int m = 0; m < 4; ++m)
            af[m] = *(const bf16x8*)&lds_w[(wm * 64 + m * 16 + l15) * 40 + (l4 << 3)];
        #pragma unroll
        for (int n = 0; n < 4; ++n)
            bfr[n] = *(const bf16x8*)&lds_x[(wn * 64 + n * 16 + l15) * 40 + (l4 << 3)];
        #pragma unroll
        for (int m = 0; m < 4; ++m)
            #pragma unroll
            for (int n = 0; n < 4; ++n)
                acc[m][n] = MFMA(af[m], bfr[n], acc[m][n]);
    }
    // epilogue: o-block (128-aligned) sits in exactly one (head, q/k/v) chunk
    const int h = o0 / 384, which = (o0 % 384) / 128;
    const int bh = b * NH + h;
    #pragma unroll
    for (int m = 0; m < 4; ++m) {
        const int d0 = wm * 64 + m * 16 + (l4 << 2);   // 4 consecutive d (regs)
        float bia[4];
        #pragma unroll
        for (int r = 0; r < 4; ++r) bia[r] = bias[o0 + d0 + r];
        #pragma unroll
        for (int n = 0; n < 4; ++n) {
            const int i = i0 + wn * 64 + n * 16 + l15;
            float v0 = acc[m][n][0] + bia[0], v1 = acc[m][n][1] + bia[1];
            float v2 = acc[m][n][2] + bia[2], v3 = acc[m][n][3] + bia[3];
            if (which == 2) {                     // v: transposed store [bh][d][i]
                vtb[((size_t)bh * DK + d0 + 0) * SEQ + i] = f2bf(v0);
                vtb[((size_t)bh * DK + d0 + 1) * SEQ + i] = f2bf(v1);
                vtb[((size_t)bh * DK + d0 + 2) * SEQ + i] = f2bf(v2);
                vtb[((size_t)bh * DK + d0 + 3) * SEQ + i] = f2bf(v3);
            } else {                              // q/k: [bh][i][d], 8B packed
                ushort* dst = (which == 0) ? qb : kb;
                uint2 p; p.x = pk2(v0, v1); p.y = pk2(v2, v3);
                *(uint2*)&dst[((size_t)bh * SEQ + i) * DK + d0] = p;
            }
        }
    }
}

// ---------------------------------------------------------------------------
// k2: column-softmax stats via S^T = K * Q^T.
// D[m=j][n=i]: softmax axis i lands in the lane dim -> per-lane online (m,s),
// final merge = 4x shfl_xor over the 16-lane i-group.  K frags hoisted in regs.
// Block: 4 waves, each owns j32; j-tile 128.  mstat/rstat per (bh, j).
// ---------------------------------------------------------------------------
__global__ __launch_bounds__(256) void stats_kernel(
    const ushort* __restrict__ qb, const ushort* __restrict__ kb,
    float* __restrict__ mstat, float* __restrict__ rstat)
{
    __shared__ ushort lds_q[64 * 136];   // [i][d], stride 272B => 2-way max
    const int tid = threadIdx.x;
    const int lane = tid & 63, wv = tid >> 6;
    const int l15 = lane & 15, l4 = lane >> 4;
    const int bh = blockIdx.y;
    const int j0 = blockIdx.x * 128 + wv * 32;
    const ushort* kbase = kb + (size_t)bh * SEQ * DK;
    const ushort* qbase = qb + (size_t)bh * SEQ * DK;

    bf16x8 kf[2][4];                      // wave's K rows [j32][128] in regs
    #pragma unroll
    for (int m = 0; m < 2; ++m)
        #pragma unroll
        for (int ks = 0; ks < 4; ++ks)
            kf[m][ks] = *(const bf16x8*)&kbase[(size_t)(j0 + m * 16 + l15) * DK
                                               + ks * 32 + (l4 << 3)];
    float mm[2][4], ss[2][4];
    #pragma unroll
    for (int m = 0; m < 2; ++m)
        #pragma unroll
        for (int r = 0; r < 4; ++r) { mm[m][r] = -1e30f; ss[m][r] = 0.0f; }

    for (int it = 0; it < SEQ / 64; ++it) {
        __syncthreads();
        #pragma unroll
        for (int l = 0; l < 4; ++l) {
            int idx = tid + l * 256;
            int i = idx >> 4, dq = (idx & 15) << 3;
            *(uint4*)&lds_q[i * 136 + dq] =
                *(const uint4*)&qbase[(size_t)(it * 64 + i) * DK + dq];
        }
        __syncthreads();
        #pragma unroll
        for (int n = 0; n < 4; ++n) {
            f32x4 a0 = {}, a1 = {};
            #pragma unroll
            for (int ks = 0; ks < 4; ++ks) {
                bf16x8 bq = *(const bf16x8*)&lds_q[(n * 16 + l15) * 136
                                                   + ks * 32 + (l4 << 3)];
                a0 = MFMA(kf[0][ks], bq, a0);
                a1 = MFMA(kf[1][ks], bq, a1);
            }
            #pragma unroll
            for (int r = 0; r < 4; ++r) {
                float v0 = a0[r] * SCALE;
                float n0 = fmaxf(mm[0][r], v0);
                ss[0][r] = ss[0][r] * __expf(mm[0][r] - n0) + __expf(v0 - n0);
                mm[0][r] = n0;
                float v1 = a1[r] * SCALE;
                float n1 = fmaxf(mm[1][r], v1);
                ss[1][r] = ss[1][r] * __expf(mm[1][r] - n1) + __expf(v1 - n1);
                mm[1][r] = n1;
            }
        }
    }
    #pragma unroll
    for (int m = 0; m < 2; ++m)
        #pragma unroll
        for (int r = 0; r < 4; ++r) {
            float mv = mm[m][r], sv = ss[m][r];
            #pragma unroll
            for (int wmask = 1; wmask < 16; wmask <<= 1) {
                float mo = __shfl_xor(mv, wmask, 64);
                float so = __shfl_xor(sv, wmask, 64);
                float mn = fmaxf(mv, mo);
                sv = sv * __expf(mv - mn) + so * __expf(mo - mn);
                mv = mn;
            }
            if (l15 == 0) {
                int j = j0 + m * 16 + (l4 << 2) + r;
                mstat[(size_t)bh * SEQ + j] = mv;
                rstat[(size_t)bh * SEQ + j] = 1.0f / sv;
            }
        }
}

// ---------------------------------------------------------------------------
// k3: attention output.  Per i-tile(64): loop j-tiles(64):
//   phase A: S^T = K*Q^T (Q hoisted in regs), P = exp(scale*S - m_j)*r_j -> LDS [i][j] bf16
//   phase B: O^T = V^T * P^T accumulated; epilogue -> resb [b][i][h*128+d] bf16
// ---------------------------------------------------------------------------
__global__ __launch_bounds__(256) void attn_kernel(
    const ushort* __restrict__ qb, const ushort* __restrict__ kb,
    const ushort* __restrict__ vtb,
    const float* __restrict__ mstat, const float* __restrict__ rstat,
    ushort* __restrict__ resb)
{
    __shared__ ushort lds_k[64 * 136];    // [j][d]
    __shared__ ushort lds_vt[128 * 72];   // [d][j]
    __shared__ ushort lds_p[64 * 72];     // [i][j]
    const int tid = threadIdx.x;
    const int lane = tid & 63, wv = tid >> 6;
    const int l15 = lane & 15, l4 = lane >> 4;
    const int wj = wv & 1, wi = wv >> 1;            // phase-A wave tile (j32 x i32)
    const int bh = blockIdx.y, b = bh >> 2, h = bh & 3;
    const int i0 = blockIdx.x * 64;
    const ushort* qbase = qb + (size_t)bh * SEQ * DK;
    const ushort* kbase = kb + (size_t)bh * SEQ * DK;
    const ushort* vtbase = vtb + (size_t)bh * DK * SEQ;

    bf16x8 qf[2][4];                      // wave's Q rows [i32][128] in regs
    #pragma unroll
    for (int n = 0; n < 2; ++n)
        #pragma unroll
        for (int ks = 0; ks < 4; ++ks)
            qf[n][ks] = *(const bf16x8*)&qbase[(size_t)(i0 + wi * 32 + n * 16 + l15) * DK
                                               + ks * 32 + (l4 << 3)];
    f32x4 oacc[2][4] = {};                // phase-B tile: d32 = wv*32, i 64

    for (int jt = 0; jt < SEQ / 64; ++jt) {
        const int j0 = jt * 64;
        __syncthreads();
        #pragma unroll
        for (int l = 0; l < 4; ++l) {              // K tile [64 j][128 d]
            int idx = tid + l * 256;
            int j = idx >> 4, dq = (idx & 15) << 3;
            *(uint4*)&lds_k[j * 136 + dq] =
                *(const uint4*)&kbase[(size_t)(j0 + j) * DK + dq];
        }
        #pragma unroll
        for (int l = 0; l < 4; ++l) {              // V^T tile [128 d][64 j]
            int idx = tid + l * 256;
            int d = idx >> 3, jq = (idx & 7) << 3;
            *(uint4*)&lds_vt[d * 72 + jq] =
                *(const uint4*)&vtbase[(size_t)d * SEQ + j0 + jq];
        }
        __syncthreads();
        // ---- phase A ----
        float mj[2][4], rj[2][4];
        #pragma unroll
        for (int m = 0; m < 2; ++m)
            #pragma unroll
            for (int r = 0; r < 4; ++r) {
                int j = j0 + wj * 32 + m * 16 + (l4 << 2) + r;
                mj[m][r] = mstat[(size_t)bh * SEQ + j];
                rj[m][r] = rstat[(size_t)bh * SEQ + j];
            }
        bf16x8 af[2][4];
        #pragma unroll
        for (int m = 0; m < 2; ++m)
            #pragma unroll
            for (int ks = 0; ks < 4; ++ks)
                af[m][ks] = *(const bf16x8*)&lds_k[(wj * 32 + m * 16 + l15) * 136
                                                   + ks * 32 + (l4 << 3)];
        #pragma unroll
        for (int m = 0; m < 2; ++m)
            #pragma unroll
            for (int n = 0; n < 2; ++n) {
                f32x4 s = {};
                #pragma unroll
                for (int ks = 0; ks < 4; ++ks)
                    s = MFMA(af[m][ks], qf[n][ks], s);
                const int i = wi * 32 + n * 16 + l15;
                float p0 = __expf(s[0] * SCALE - mj[m][0]) * rj[m][0];
                float p1 = __expf(s[1] * SCALE - mj[m][1]) * rj[m][1];
                float p2 = __expf(s[2] * SCALE - mj[m][2]) * rj[m][2];
                float p3 = __expf(s[3] * SCALE - mj[m][3]) * rj[m][3];
                uint2 pp; pp.x = pk2(p0, p1); pp.y = pk2(p2, p3);
                *(uint2*)&lds_p[i * 72 + wj * 32 + m * 16 + (l4 << 2)] = pp;
            }
        __syncthreads();
        // ---- phase B ----
        #pragma unroll
        for (int ks = 0; ks < 2; ++ks) {
            bf16x8 va0 = *(const bf16x8*)&lds_vt[(wv * 32 + 0  + l15) * 72 + ks * 32 + (l4 << 3)];
            bf16x8 va1 = *(const bf16x8*)&lds_vt[(wv * 32 + 16 + l15) * 72 + ks * 32 + (l4 << 3)];
            #pragma unroll
            for (int n = 0; n < 4; ++n) {
                bf16x8 pb = *(const bf16x8*)&lds_p[(n * 16 + l15) * 72 + ks * 32 + (l4 << 3)];
                oacc[0][n] = MFMA(va0, pb, oacc[0][n]);
                oacc[1][n] = MFMA(va1, pb, oacc[1][n]);
            }
        }
    }
    // epilogue: O^T[d][i] -> resb [b][i][h*128 + d]
    #pragma unroll
    for (int m = 0; m < 2; ++m)
        #pragma unroll
        for (int n = 0; n < 4; ++n) {
            const int i = i0 + n * 16 + l15;
            const int d = wv * 32 + m * 16 + (l4 << 2);
            uint2 p;
            p.x = pk2(oacc[m][n][0], oacc[m][n][1]);
            p.y = pk2(oacc[m][n][2], oacc[m][n][3]);
            *(uint2*)&resb[((size_t)b * SEQ + i) * (NH * DK) + h * DK + d] = p;
        }
}

// ---------------------------------------------------------------------------
// k4: out projection + bias + residual.
//   out[b][c][i] = sum_k Wout[c][k]*res[i][k] + bout[c] + x[b][c][i]
// Same structure as k1.  Output fp32.
// ---------------------------------------------------------------------------
__global__ __launch_bounds__(256) void outproj_kernel(
    const ushort* __restrict__ resb, const float* __restrict__ wout,
    const float* __restrict__ bout, const float* __restrict__ x,
    float* __restrict__ out)
{
    __shared__ ushort lds_w[128 * 40];   // [c][k]
    __shared__ ushort lds_r[128 * 40];   // [i][k]
    const int tid = threadIdx.x;
    const int lane = tid & 63, wv = tid >> 6;
    const int l15 = lane & 15, l4 = lane >> 4;
    const int wm = wv >> 1, wn = wv & 1;
    const int i0 = blockIdx.x * 128, c0 = blockIdx.y * 128, b = blockIdx.z;

    f32x4 acc[4][4] = {};
    for (int k0 = 0; k0 < NH * DK; k0 += 32) {
        __syncthreads();
        #pragma unroll
        for (int l = 0; l < 4; ++l) {
            int idx = tid + l * 256;
            int c = idx >> 3, kq = (idx & 7) << 2;
            float4 v = *(const float4*)&wout[(size_t)(c0 + c) * (NH * DK) + k0 + kq];
            uint2 p; p.x = pk2(v.x, v.y); p.y = pk2(v.z, v.w);
            *(uint2*)&lds_w[c * 40 + kq] = p;
        }
        #pragma unroll
        for (int l = 0; l < 2; ++l) {
            int idx = tid + l * 256;
            int i = idx >> 2, kq = (idx & 3) << 3;
            *(uint4*)&lds_r[i * 40 + kq] =
                *(const uint4*)&resb[((size_t)b * SEQ + i0 + i) * (NH * DK) + k0 + kq];
        }
        __syncthreads();
        bf16x8 af[4], bfr[4];
        #pragma unroll
        for (int m = 0; m < 4; ++m)
            af[m] = *(const bf16x8*)&lds_w[(wm * 64 + m * 16 + l15) * 40 + (l4 << 3)];
        #pragma unroll
        for (int n = 0; n < 4; ++n)
            bfr[n] = *(const bf16x8*)&lds_r[(wn * 64 + n * 16 + l15) * 40 + (l4 << 3)];
        #pragma unroll
        for (int m = 0; m < 4; ++m)
            #pragma unroll
            for (int n = 0; n < 4; ++n)
                acc[m][n] = MFMA(af[m], bfr[n], acc[m][n]);
    }
    #pragma unroll
    for (int m = 0; m < 4; ++m) {
        const int cb = c0 + wm * 64 + m * 16 + (l4 << 2);
        float bia[4];
        #pragma unroll
        for (int r = 0; r < 4; ++r) bia[r] = bout[cb + r];
        #pragma unroll
        for (int n = 0; n < 4; ++n) {
            const int i = i0 + wn * 64 + n * 16 + l15;
            #pragma unroll
            for (int r = 0; r < 4; ++r) {
                size_t off = ((size_t)b * CIN + cb + r) * SEQ + i;
                out[off] = acc[m][n][r] + bia[r] + x[off];
            }
        }
    }
}

// ---------------------------------------------------------------------------
extern "C" void kernel_launch(void* const* d_in, const int* in_sizes, int n_in,
                              void* d_out, int out_size, void* d_ws, size_t ws_size,
                              hipStream_t stream) {
    const float* x      = (const float*)d_in[0];
    const float* w_proj = (const float*)d_in[1];
    const float* b_proj = (const float*)d_in[2];
    const float* w_out  = (const float*)d_in[3];
    const float* b_out  = (const float*)d_in[4];
    // n_heads (d_in[5]) hardcoded = 4

    const size_t xtE  = (size_t)B_ * SEQ * CIN;        // bf16 elements
    const size_t qkE  = (size_t)B_ * NH * SEQ * DK;    // bf16 elements
    ushort* xt    = (ushort*)d_ws;
    ushort* qb    = xt + xtE;
    ushort* kb    = qb + qkE;
    ushort* vtb   = kb + qkE;
    float*  mstat = (float*)(vtb + qkE);
    float*  rstat = mstat + (size_t)B_ * NH * SEQ;
    ushort* resb  = (ushort*)(rstat + (size_t)B_ * NH * SEQ);
    float*  out   = (float*)d_out;
    // total ws: 2*(8.4M + 3*8.4M) + 512K + 16.8M  ~= 84.4 MB

    transpose_cast_kernel<<<dim3(SEQ / 64, CIN / 64, B_), 256, 0, stream>>>(x, xt);
    qkv_kernel<<<dim3(OUT3 / 128, SEQ / 128, B_), 256, 0, stream>>>(
        w_proj, b_proj, xt, qb, kb, vtb);
    stats_kernel<<<dim3(SEQ / 128, B_ * NH), 256, 0, stream>>>(qb, kb, mstat, rstat);
    attn_kernel<<<dim3(SEQ / 64, B_ * NH), 256, 0, stream>>>(
        qb, kb, vtb, mstat, rstat, resb);
    outproj_kernel<<<dim3(SEQ / 128, CIN / 128, B_), 256, 0, stream>>>(
        resb, w_out, b_out, x, out);
}

// Round 3
// 259.693 us; speedup vs baseline: 1.0910x; 1.0910x over previous
//
#include <hip/hip_runtime.h>
#include <hip/hip_bf16.h>
#include <math.h>

// Problem constants (fixed by setup_inputs)
#define B_    16
#define CIN   512
#define SEQ   1024
#define NH    4
#define DK    128
#define OUT3  1536
#define SCALE 0.08838834764831845f   // 1/sqrt(128)

typedef __attribute__((ext_vector_type(8))) __bf16 bf16x8;   // MFMA A/B frag
typedef __attribute__((ext_vector_type(4))) float f32x4;     // MFMA C/D frag

#define MFMA(a, b, c) __builtin_amdgcn_mfma_f32_16x16x32_bf16((a), (b), (c), 0, 0, 0)

__device__ __forceinline__ ushort f2bf(float f) {
    __hip_bfloat16 h = __float2bfloat16(f);   // RTNE
    return *(ushort*)&h;
}
__device__ __forceinline__ uint pk2(float a, float b) {
    return (uint)f2bf(a) | ((uint)f2bf(b) << 16);
}
// async global->LDS, 16B per lane; lds dest must be wave-uniform base (HW adds lane*16)
__device__ __forceinline__ void g2l16(const ushort* g, ushort* l) {
    __builtin_amdgcn_global_load_lds(
        (const __attribute__((address_space(1))) unsigned int*)g,
        (__attribute__((address_space(3))) unsigned int*)l, 16, 0, 0);
}
// T1: bijective XCD-chunked remap (nwg % 8 == 0 for all our grids)
__device__ __forceinline__ int xcdswz(int bid, int nwg) {
    return (bid & 7) * (nwg >> 3) + (bid >> 3);
}

// ---------------------------------------------------------------------------
// k0: x [B][C][seq] fp32 -> xt [B][seq][C] bf16  (LDS transpose, 64x64 tile)
// ---------------------------------------------------------------------------
__global__ __launch_bounds__(256) void transpose_cast_kernel(
    const float* __restrict__ x, ushort* __restrict__ xt)
{
    __shared__ ushort t[64 * 66];
    const int tid = threadIdx.x;
    const int i0 = blockIdx.x * 64, c0 = blockIdx.y * 64, b = blockIdx.z;

    #pragma unroll
    for (int l = 0; l < 4; ++l) {
        int idx = tid + l * 256;
        int c = idx >> 4, i4 = (idx & 15) << 2;
        float4 v = *(const float4*)&x[((size_t)b * CIN + c0 + c) * SEQ + i0 + i4];
        t[(i4 + 0) * 66 + c] = f2bf(v.x);
        t[(i4 + 1) * 66 + c] = f2bf(v.y);
        t[(i4 + 2) * 66 + c] = f2bf(v.z);
        t[(i4 + 3) * 66 + c] = f2bf(v.w);
    }
    __syncthreads();
    #pragma unroll
    for (int l = 0; l < 4; ++l) {
        int idx = tid + l * 256;
        int i = idx >> 4, c4 = (idx & 15) << 2;
        uint2 p;
        p.x = *(const uint*)&t[i * 66 + c4];
        p.y = *(const uint*)&t[i * 66 + c4 + 2];
        *(uint2*)&xt[((size_t)b * SEQ + i0 + i) * CIN + c0 + c4] = p;
    }
}

// ---------------------------------------------------------------------------
// prep: fp32 -> bf16 cast (for w_proj / w_out), 1 float4 per thread
// ---------------------------------------------------------------------------
__global__ __launch_bounds__(256) void cast_kernel(
    const float* __restrict__ src, ushort* __restrict__ dst, int n4)
{
    int idx = blockIdx.x * 256 + threadIdx.x;
    if (idx < n4) {
        float4 v = *(const float4*)&src[(size_t)idx * 4];
        uint2 p; p.x = pk2(v.x, v.y); p.y = pk2(v.z, v.w);
        *(uint2*)&dst[(size_t)idx * 4] = p;
    }
}

// ---------------------------------------------------------------------------
// k1: QKV projection.  D[o][i] = sum_c Wbf[o][c] * xt[i][c]  (+bias)
// m97 structure: 128x128 block, BK=32, global_load_lds staging, linear LDS.
// q,k -> [bh][seq][128] bf16 ; v -> TRANSPOSED [bh][128][seq] bf16.
// ---------------------------------------------------------------------------
__global__ __launch_bounds__(256) void qkv_kernel(
    const ushort* __restrict__ wbf, const float* __restrict__ bias,
    const ushort* __restrict__ xt,
    ushort* __restrict__ qb, ushort* __restrict__ kb, ushort* __restrict__ vtb)
{
    __shared__ __attribute__((aligned(16))) ushort lds_a[128 * 32];  // [o][c] linear
    __shared__ __attribute__((aligned(16))) ushort lds_b[128 * 32];  // [i][c] linear
    const int tid = threadIdx.x;
    const int lane = tid & 63, wv = tid >> 6;
    const int l15 = lane & 15, l4 = lane >> 4;
    const int wm = wv >> 1, wn = wv & 1;
    const int swz = xcdswz(blockIdx.x, 1536);
    const int o0 = (swz % 12) * 128;
    const int i0 = ((swz / 12) & 7) * 128;
    const int b  = swz / 96;

    f32x4 acc[4][4] = {};
    for (int c0 = 0; c0 < CIN; c0 += 32) {
        __syncthreads();
        #pragma unroll
        for (int l = 0; l < 2; ++l) {          // A tile 128x32 bf16 (8KB)
            int chunk = l * 256 + tid;
            int row = chunk >> 2, c = chunk & 3;
            g2l16(&wbf[(size_t)(o0 + row) * CIN + c0 + (c << 3)],
                  &lds_a[(size_t)(l * 256 + wv * 64) * 8]);
        }
        #pragma unroll
        for (int l = 0; l < 2; ++l) {          // B tile 128x32 bf16 (8KB)
            int chunk = l * 256 + tid;
            int row = chunk >> 2, c = chunk & 3;
            g2l16(&xt[((size_t)b * SEQ + i0 + row) * CIN + c0 + (c << 3)],
                  &lds_b[(size_t)(l * 256 + wv * 64) * 8]);
        }
        __syncthreads();
        bf16x8 af[4], bfv[4];
        #pragma unroll
        for (int m = 0; m < 4; ++m)
            af[m] = *(const bf16x8*)&lds_a[(wm * 64 + m * 16 + l15) * 32 + (l4 << 3)];
        #pragma unroll
        for (int n = 0; n < 4; ++n)
            bfv[n] = *(const bf16x8*)&lds_b[(wn * 64 + n * 16 + l15) * 32 + (l4 << 3)];
        #pragma unroll
        for (int m = 0; m < 4; ++m)
            #pragma unroll
            for (int n = 0; n < 4; ++n)
                acc[m][n] = MFMA(af[m], bfv[n], acc[m][n]);
    }
    // epilogue: o-block (128-aligned) sits in exactly one (head, q/k/v) chunk
    const int h = o0 / 384, which = (o0 % 384) / 128;
    const int bh = b * NH + h;
    #pragma unroll
    for (int m = 0; m < 4; ++m) {
        const int d0 = wm * 64 + m * 16 + (l4 << 2);
        float bia[4];
        #pragma unroll
        for (int r = 0; r < 4; ++r) bia[r] = bias[o0 + d0 + r];
        #pragma unroll
        for (int n = 0; n < 4; ++n) {
            const int i = i0 + wn * 64 + n * 16 + l15;
            float v0 = acc[m][n][0] + bia[0], v1 = acc[m][n][1] + bia[1];
            float v2 = acc[m][n][2] + bia[2], v3 = acc[m][n][3] + bia[3];
            if (which == 2) {                     // v: transposed store [bh][d][i]
                vtb[((size_t)bh * DK + d0 + 0) * SEQ + i] = f2bf(v0);
                vtb[((size_t)bh * DK + d0 + 1) * SEQ + i] = f2bf(v1);
                vtb[((size_t)bh * DK + d0 + 2) * SEQ + i] = f2bf(v2);
                vtb[((size_t)bh * DK + d0 + 3) * SEQ + i] = f2bf(v3);
            } else {                              // q/k: [bh][i][d], 8B packed
                ushort* dst = (which == 0) ? qb : kb;
                uint2 p; p.x = pk2(v0, v1); p.y = pk2(v2, v3);
                *(uint2*)&dst[((size_t)bh * SEQ + i) * DK + d0] = p;
            }
        }
    }
}

// ---------------------------------------------------------------------------
// k2: column-softmax stats via S^T = K * Q^T  (softmax axis i in lane dim).
// Q tile staged via global_load_lds with XOR-swizzled source (rows 256B).
// ---------------------------------------------------------------------------
__global__ __launch_bounds__(256) void stats_kernel(
    const ushort* __restrict__ qb, const ushort* __restrict__ kb,
    float* __restrict__ mstat, float* __restrict__ rstat)
{
    __shared__ __attribute__((aligned(16))) ushort lds_q[64 * 128];  // swizzled
    const int tid = threadIdx.x;
    const int lane = tid & 63, wv = tid >> 6;
    const int l15 = lane & 15, l4 = lane >> 4;
    const int swz = xcdswz(blockIdx.x, 512);
    const int bh = swz >> 3;
    const int j0 = (swz & 7) * 128 + wv * 32;
    const ushort* kbase = kb + (size_t)bh * SEQ * DK;
    const ushort* qbase = qb + (size_t)bh * SEQ * DK;

    bf16x8 kf[2][4];                      // wave's K rows [j32][128] in regs
    #pragma unroll
    for (int m = 0; m < 2; ++m)
        #pragma unroll
        for (int ks = 0; ks < 4; ++ks)
            kf[m][ks] = *(const bf16x8*)&kbase[(size_t)(j0 + m * 16 + l15) * DK
                                               + ks * 32 + (l4 << 3)];
    float mm[2][4], ss[2][4];
    #pragma unroll
    for (int m = 0; m < 2; ++m)
        #pragma unroll
        for (int r = 0; r < 4; ++r) { mm[m][r] = -1e30f; ss[m][r] = 0.0f; }

    for (int it = 0; it < SEQ / 64; ++it) {
        __syncthreads();
        #pragma unroll
        for (int l = 0; l < 4; ++l) {          // Q tile 64x128 bf16, swz source
            int chunk = l * 256 + tid;
            int row = chunk >> 4, c = chunk & 15;
            g2l16(&qbase[(size_t)(it * 64 + row) * DK + ((c ^ (row & 7)) << 3)],
                  &lds_q[(size_t)(l * 256 + wv * 64) * 8]);
        }
        __syncthreads();
        f32x4 sa0[4], sa1[4];
        #pragma unroll
        for (int n = 0; n < 4; ++n) {
            f32x4 a0 = {}, a1 = {};
            #pragma unroll
            for (int ks = 0; ks < 4; ++ks) {
                bf16x8 bq = *(const bf16x8*)&lds_q[(n * 16 + l15) * 128
                                + ((((ks << 2) | l4) ^ (l15 & 7)) << 3)];
                a0 = MFMA(kf[0][ks], bq, a0);
                a1 = MFMA(kf[1][ks], bq, a1);
            }
            sa0[n] = a0; sa1[n] = a1;
        }
        #pragma unroll
        for (int r = 0; r < 4; ++r) {
            {   // m = 0
                float v0 = sa0[0][r] * SCALE, v1 = sa0[1][r] * SCALE;
                float v2 = sa0[2][r] * SCALE, v3 = sa0[3][r] * SCALE;
                float tm = fmaxf(fmaxf(v0, v1), fmaxf(v2, v3));
                float nm = fmaxf(mm[0][r], tm);
                float s4 = __expf(v0 - nm) + __expf(v1 - nm)
                         + __expf(v2 - nm) + __expf(v3 - nm);
                ss[0][r] = ss[0][r] * __expf(mm[0][r] - nm) + s4;
                mm[0][r] = nm;
            }
            {   // m = 1
                float v0 = sa1[0][r] * SCALE, v1 = sa1[1][r] * SCALE;
                float v2 = sa1[2][r] * SCALE, v3 = sa1[3][r] * SCALE;
                float tm = fmaxf(fmaxf(v0, v1), fmaxf(v2, v3));
                float nm = fmaxf(mm[1][r], tm);
                float s4 = __expf(v0 - nm) + __expf(v1 - nm)
                         + __expf(v2 - nm) + __expf(v3 - nm);
                ss[1][r] = ss[1][r] * __expf(mm[1][r] - nm) + s4;
                mm[1][r] = nm;
            }
        }
    }
    #pragma unroll
    for (int m = 0; m < 2; ++m)
        #pragma unroll
        for (int r = 0; r < 4; ++r) {
            float mv = mm[m][r], sv = ss[m][r];
            #pragma unroll
            for (int wmask = 1; wmask < 16; wmask <<= 1) {
                float mo = __shfl_xor(mv, wmask, 64);
                float so = __shfl_xor(sv, wmask, 64);
                float mn = fmaxf(mv, mo);
                sv = sv * __expf(mv - mn) + so * __expf(mo - mn);
                mv = mn;
            }
            if (l15 == 0) {
                int j = j0 + m * 16 + (l4 << 2) + r;
                mstat[(size_t)bh * SEQ + j] = mv;
                rstat[(size_t)bh * SEQ + j] = 1.0f / sv;
            }
        }
}

// ---------------------------------------------------------------------------
// k3: attention output.  Per i-tile(64): loop j-tiles(64):
//   A: S^T = K*Q^T (Q in regs), P = exp(scale*S - m_j)*r_j -> LDS [i][j] bf16
//   B: O^T = V^T * P^T accumulated -> resb [b][i][h*128+d] bf16
// K / V^T staged via global_load_lds with XOR-swizzled source.
// ---------------------------------------------------------------------------
__global__ __launch_bounds__(256) void attn_kernel(
    const ushort* __restrict__ qb, const ushort* __restrict__ kb,
    const ushort* __restrict__ vtb,
    const float* __restrict__ mstat, const float* __restrict__ rstat,
    ushort* __restrict__ resb)
{
    __shared__ __attribute__((aligned(16))) ushort lds_k[64 * 128];   // [j][d] swz
    __shared__ __attribute__((aligned(16))) ushort lds_vt[128 * 64];  // [d][j] swz
    __shared__ __attribute__((aligned(16))) ushort lds_p[64 * 72];    // [i][j] pad
    const int tid = threadIdx.x;
    const int lane = tid & 63, wv = tid >> 6;
    const int l15 = lane & 15, l4 = lane >> 4;
    const int wj = wv & 1, wi = wv >> 1;
    const int swz = xcdswz(blockIdx.x, 1024);
    const int bh = swz >> 4, b = bh >> 2, h = bh & 3;
    const int i0 = (swz & 15) * 64;
    const ushort* qbase = qb + (size_t)bh * SEQ * DK;
    const ushort* kbase = kb + (size_t)bh * SEQ * DK;
    const ushort* vtbase = vtb + (size_t)bh * DK * SEQ;

    bf16x8 qf[2][4];                      // wave's Q rows [i32][128] in regs
    #pragma unroll
    for (int n = 0; n < 2; ++n)
        #pragma unroll
        for (int ks = 0; ks < 4; ++ks)
            qf[n][ks] = *(const bf16x8*)&qbase[(size_t)(i0 + wi * 32 + n * 16 + l15) * DK
                                               + ks * 32 + (l4 << 3)];
    f32x4 oacc[2][4] = {};

    for (int jt = 0; jt < SEQ / 64; ++jt) {
        const int j0 = jt * 64;
        __syncthreads();
        #pragma unroll
        for (int l = 0; l < 4; ++l) {              // K tile [64][128] (16KB) swz
            int chunk = l * 256 + tid;
            int row = chunk >> 4, c = chunk & 15;
            g2l16(&kbase[(size_t)(j0 + row) * DK + ((c ^ (row & 7)) << 3)],
                  &lds_k[(size_t)(l * 256 + wv * 64) * 8]);
        }
        #pragma unroll
        for (int l = 0; l < 4; ++l) {              // V^T tile [128][64] (16KB) swz
            int chunk = l * 256 + tid;
            int row = chunk >> 3, c = chunk & 7;
            g2l16(&vtbase[(size_t)row * SEQ + j0 + ((c ^ (row & 7)) << 3)],
                  &lds_vt[(size_t)(l * 256 + wv * 64) * 8]);
        }
        __syncthreads();
        // ---- phase A ----
        float mj[2][4], rj[2][4];
        #pragma unroll
        for (int m = 0; m < 2; ++m)
            #pragma unroll
            for (int r = 0; r < 4; ++r) {
                int j = j0 + wj * 32 + m * 16 + (l4 << 2) + r;
                mj[m][r] = mstat[(size_t)bh * SEQ + j];
                rj[m][r] = rstat[(size_t)bh * SEQ + j];
            }
        bf16x8 af[2][4];
        #pragma unroll
        for (int m = 0; m < 2; ++m)
            #pragma unroll
            for (int ks = 0; ks < 4; ++ks)
                af[m][ks] = *(const bf16x8*)&lds_k[(wj * 32 + m * 16 + l15) * 128
                                + ((((ks << 2) | l4) ^ (l15 & 7)) << 3)];
        #pragma unroll
        for (int m = 0; m < 2; ++m)
            #pragma unroll
            for (int n = 0; n < 2; ++n) {
                f32x4 s = {};
                #pragma unroll
                for (int ks = 0; ks < 4; ++ks)
                    s = MFMA(af[m][ks], qf[n][ks], s);
                const int i = wi * 32 + n * 16 + l15;
                float p0 = __expf(s[0] * SCALE - mj[m][0]) * rj[m][0];
                float p1 = __expf(s[1] * SCALE - mj[m][1]) * rj[m][1];
                float p2 = __expf(s[2] * SCALE - mj[m][2]) * rj[m][2];
                float p3 = __expf(s[3] * SCALE - mj[m][3]) * rj[m][3];
                uint2 pp; pp.x = pk2(p0, p1); pp.y = pk2(p2, p3);
                *(uint2*)&lds_p[i * 72 + wj * 32 + m * 16 + (l4 << 2)] = pp;
            }
        __syncthreads();
        // ---- phase B ----
        #pragma unroll
        for (int ks = 0; ks < 2; ++ks) {
            bf16x8 va0 = *(const bf16x8*)&lds_vt[(wv * 32 + l15) * 64
                            + ((((ks << 2) | l4) ^ (l15 & 7)) << 3)];
            bf16x8 va1 = *(const bf16x8*)&lds_vt[(wv * 32 + 16 + l15) * 64
                            + ((((ks << 2) | l4) ^ (l15 & 7)) << 3)];
            #pragma unroll
            for (int n = 0; n < 4; ++n) {
                bf16x8 pb = *(const bf16x8*)&lds_p[(n * 16 + l15) * 72
                                + ks * 32 + (l4 << 3)];
                oacc[0][n] = MFMA(va0, pb, oacc[0][n]);
                oacc[1][n] = MFMA(va1, pb, oacc[1][n]);
            }
        }
    }
    // epilogue: O^T[d][i] -> resb [b][i][h*128 + d]
    #pragma unroll
    for (int m = 0; m < 2; ++m)
        #pragma unroll
        for (int n = 0; n < 4; ++n) {
            const int i = i0 + n * 16 + l15;
            const int d = wv * 32 + m * 16 + (l4 << 2);
            uint2 p;
            p.x = pk2(oacc[m][n][0], oacc[m][n][1]);
            p.y = pk2(oacc[m][n][2], oacc[m][n][3]);
            *(uint2*)&resb[((size_t)b * SEQ + i) * (NH * DK) + h * DK + d] = p;
        }
}

// ---------------------------------------------------------------------------
// k4: out projection + bias + residual (m97 structure, bf16 W preconverted).
//   out[b][c][i] = sum_k Woutbf[c][k]*res[i][k] + bout[c] + x[b][c][i]
// ---------------------------------------------------------------------------
__global__ __launch_bounds__(256) void outproj_kernel(
    const ushort* __restrict__ resb, const ushort* __restrict__ woutbf,
    const float* __restrict__ bout, const float* __restrict__ x,
    float* __restrict__ out)
{
    __shared__ __attribute__((aligned(16))) ushort lds_a[128 * 32];  // [c][k]
    __shared__ __attribute__((aligned(16))) ushort lds_b[128 * 32];  // [i][k]
    const int tid = threadIdx.x;
    const int lane = tid & 63, wv = tid >> 6;
    const int l15 = lane & 15, l4 = lane >> 4;
    const int wm = wv >> 1, wn = wv & 1;
    const int swz = xcdswz(blockIdx.x, 512);
    const int i0 = (swz & 7) * 128;
    const int c0 = ((swz >> 3) & 3) * 128;
    const int b  = swz >> 5;

    f32x4 acc[4][4] = {};
    for (int k0 = 0; k0 < NH * DK; k0 += 32) {
        __syncthreads();
        #pragma unroll
        for (int l = 0; l < 2; ++l) {
            int chunk = l * 256 + tid;
            int row = chunk >> 2, c = chunk & 3;
            g2l16(&woutbf[(size_t)(c0 + row) * (NH * DK) + k0 + (c << 3)],
                  &lds_a[(size_t)(l * 256 + wv * 64) * 8]);
        }
        #pragma unroll
        for (int l = 0; l < 2; ++l) {
            int chunk = l * 256 + tid;
            int row = chunk >> 2, c = chunk & 3;
            g2l16(&resb[((size_t)b * SEQ + i0 + row) * (NH * DK) + k0 + (c << 3)],
                  &lds_b[(size_t)(l * 256 + wv * 64) * 8]);
        }
        __syncthreads();
        bf16x8 af[4], bfv[4];
        #pragma unroll
        for (int m = 0; m < 4; ++m)
            af[m] = *(const bf16x8*)&lds_a[(wm * 64 + m * 16 + l15) * 32 + (l4 << 3)];
        #pragma unroll
        for (int n = 0; n < 4; ++n)
            bfv[n] = *(const bf16x8*)&lds_b[(wn * 64 + n * 16 + l15) * 32 + (l4 << 3)];
        #pragma unroll
        for (int m = 0; m < 4; ++m)
            #pragma unroll
            for (int n = 0; n < 4; ++n)
                acc[m][n] = MFMA(af[m], bfv[n], acc[m][n]);
    }
    #pragma unroll
    for (int m = 0; m < 4; ++m) {
        const int cb = c0 + wm * 64 + m * 16 + (l4 << 2);
        float bia[4];
        #pragma unroll
        for (int r = 0; r < 4; ++r) bia[r] = bout[cb + r];
        #pragma unroll
        for (int n = 0; n < 4; ++n) {
            const int i = i0 + wn * 64 + n * 16 + l15;
            #pragma unroll
            for (int r = 0; r < 4; ++r) {
                size_t off = ((size_t)b * CIN + cb + r) * SEQ + i;
                out[off] = acc[m][n][r] + bia[r] + x[off];
            }
        }
    }
}

// ---------------------------------------------------------------------------
extern "C" void kernel_launch(void* const* d_in, const int* in_sizes, int n_in,
                              void* d_out, int out_size, void* d_ws, size_t ws_size,
                              hipStream_t stream) {
    const float* x      = (const float*)d_in[0];
    const float* w_proj = (const float*)d_in[1];
    const float* b_proj = (const float*)d_in[2];
    const float* w_out  = (const float*)d_in[3];
    const float* b_out  = (const float*)d_in[4];
    // n_heads (d_in[5]) hardcoded = 4

    const size_t xtE = (size_t)B_ * SEQ * CIN;        // bf16 elements
    const size_t qkE = (size_t)B_ * NH * SEQ * DK;    // bf16 elements
    ushort* xt    = (ushort*)d_ws;
    ushort* qb    = xt + xtE;
    ushort* kb    = qb + qkE;
    ushort* vtb   = kb + qkE;
    float*  mstat = (float*)(vtb + qkE);
    float*  rstat = mstat + (size_t)B_ * NH * SEQ;
    ushort* resb  = (ushort*)(rstat + (size_t)B_ * NH * SEQ);
    ushort* wobf  = resb + (size_t)B_ * SEQ * (NH * DK);
    // wpbf aliases resb: wpbf live only prep->qkv; resb written first in attn.
    ushort* wpbf  = resb;
    float*  out   = (float*)d_out;

    transpose_cast_kernel<<<dim3(SEQ / 64, CIN / 64, B_), 256, 0, stream>>>(x, xt);
    cast_kernel<<<dim3(768), 256, 0, stream>>>(w_proj, wpbf, 196608);  // 1536*512/4
    cast_kernel<<<dim3(256), 256, 0, stream>>>(w_out, wobf, 65536);    // 512*512/4
    qkv_kernel<<<dim3(1536), 256, 0, stream>>>(wpbf, b_proj, xt, qb, kb, vtb);
    stats_kernel<<<dim3(512), 256, 0, stream>>>(qb, kb, mstat, rstat);
    attn_kernel<<<dim3(1024), 256, 0, stream>>>(qb, kb, vtb, mstat, rstat, resb);
    outproj_kernel<<<dim3(512), 256, 0, stream>>>(resb, wobf, b_out, x, out);
}

// Round 5
// 250.202 us; speedup vs baseline: 1.1324x; 1.0379x over previous
//
#include <hip/hip_runtime.h>
#include <hip/hip_bf16.h>
#include <math.h>

// Problem constants (fixed by setup_inputs)
#define B_    16
#define CIN   512
#define SEQ   1024
#define NH    4
#define DK    128
#define OUT3  1536
#define SCALE 0.08838834764831845f   // 1/sqrt(128)

typedef __attribute__((ext_vector_type(8))) __bf16 bf16x8;   // MFMA A/B frag
typedef __attribute__((ext_vector_type(4))) float f32x4;     // MFMA C/D frag

#define MFMA(a, b, c) __builtin_amdgcn_mfma_f32_16x16x32_bf16((a), (b), (c), 0, 0, 0)

__device__ __forceinline__ ushort f2bf(float f) {
    __hip_bfloat16 h = __float2bfloat16(f);   // RTNE
    return *(ushort*)&h;
}
__device__ __forceinline__ uint pk2(float a, float b) {
    return (uint)f2bf(a) | ((uint)f2bf(b) << 16);
}
// async global->LDS, 16B per lane; lds dest is wave-uniform base (HW adds lane*16)
__device__ __forceinline__ void g2l16(const ushort* g, ushort* l) {
    __builtin_amdgcn_global_load_lds(
        (const __attribute__((address_space(1))) unsigned int*)g,
        (__attribute__((address_space(3))) unsigned int*)l, 16, 0, 0);
}
// T1: bijective XCD-chunked remap (nwg % 8 == 0 for all our grids)
__device__ __forceinline__ int xcdswz(int bid, int nwg) {
    return (bid & 7) * (nwg >> 3) + (bid >> 3);
}

// ---------------------------------------------------------------------------
// k0: x [B][C][seq] fp32 -> xt [B][seq][C] bf16  (LDS transpose, 64x64 tile)
// ---------------------------------------------------------------------------
__global__ __launch_bounds__(256) void transpose_cast_kernel(
    const float* __restrict__ x, ushort* __restrict__ xt)
{
    __shared__ ushort t[64 * 66];
    const int tid = threadIdx.x;
    const int i0 = blockIdx.x * 64, c0 = blockIdx.y * 64, b = blockIdx.z;

    #pragma unroll
    for (int l = 0; l < 4; ++l) {
        int idx = tid + l * 256;
        int c = idx >> 4, i4 = (idx & 15) << 2;
        float4 v = *(const float4*)&x[((size_t)b * CIN + c0 + c) * SEQ + i0 + i4];
        t[(i4 + 0) * 66 + c] = f2bf(v.x);
        t[(i4 + 1) * 66 + c] = f2bf(v.y);
        t[(i4 + 2) * 66 + c] = f2bf(v.z);
        t[(i4 + 3) * 66 + c] = f2bf(v.w);
    }
    __syncthreads();
    #pragma unroll
    for (int l = 0; l < 4; ++l) {
        int idx = tid + l * 256;
        int i = idx >> 4, c4 = (idx & 15) << 2;
        uint2 p;
        p.x = *(const uint*)&t[i * 66 + c4];
        p.y = *(const uint*)&t[i * 66 + c4 + 2];
        *(uint2*)&xt[((size_t)b * SEQ + i0 + i) * CIN + c0 + c4] = p;
    }
}

// ---------------------------------------------------------------------------
// prep: fp32 -> bf16 cast (for w_proj / w_out), 1 float4 per thread
// ---------------------------------------------------------------------------
__global__ __launch_bounds__(256) void cast_kernel(
    const float* __restrict__ src, ushort* __restrict__ dst, int n4)
{
    int idx = blockIdx.x * 256 + threadIdx.x;
    if (idx < n4) {
        float4 v = *(const float4*)&src[(size_t)idx * 4];
        uint2 p; p.x = pk2(v.x, v.y); p.y = pk2(v.z, v.w);
        *(uint2*)&dst[(size_t)idx * 4] = p;
    }
}

// ---------------------------------------------------------------------------
// k1: QKV projection.  D[o][i] = sum_c Wbf[o][c] * xt[i][c]  (+bias)
// 128x128 block, BK=32, double-buffered global_load_lds with prefetch-before-
// compute (T3-minimum).  q,k -> [bh][seq][128]; v -> TRANSPOSED [bh][128][seq].
// ---------------------------------------------------------------------------
__global__ __launch_bounds__(256) void qkv_kernel(
    const ushort* __restrict__ wbf, const float* __restrict__ bias,
    const ushort* __restrict__ xt,
    ushort* __restrict__ qb, ushort* __restrict__ kb, ushort* __restrict__ vtb)
{
    __shared__ __attribute__((aligned(16))) ushort lds_a0[128 * 32];
    __shared__ __attribute__((aligned(16))) ushort lds_a1[128 * 32];
    __shared__ __attribute__((aligned(16))) ushort lds_b0[128 * 32];
    __shared__ __attribute__((aligned(16))) ushort lds_b1[128 * 32];
    const int tid = threadIdx.x;
    const int lane = tid & 63, wv = tid >> 6;
    const int l15 = lane & 15, l4 = lane >> 4;
    const int wm = wv >> 1, wn = wv & 1;
    const int swz = xcdswz(blockIdx.x, 1536);
    const int o0 = (swz % 12) * 128;
    const int i0 = ((swz / 12) & 7) * 128;
    const int b  = swz / 96;

    auto stage = [&](int c0, ushort* la, ushort* lb) {
        #pragma unroll
        for (int l = 0; l < 2; ++l) {
            int chunk = l * 256 + tid;
            int row = chunk >> 2, c = chunk & 3;
            g2l16(&wbf[(size_t)(o0 + row) * CIN + c0 + (c << 3)],
                  &la[(size_t)(l * 256 + wv * 64) * 8]);
        }
        #pragma unroll
        for (int l = 0; l < 2; ++l) {
            int chunk = l * 256 + tid;
            int row = chunk >> 2, c = chunk & 3;
            g2l16(&xt[((size_t)b * SEQ + i0 + row) * CIN + c0 + (c << 3)],
                  &lb[(size_t)(l * 256 + wv * 64) * 8]);
        }
    };

    f32x4 acc[4][4] = {};
    stage(0, lds_a0, lds_b0);
    __syncthreads();
    for (int it = 0; it < CIN / 32; ++it) {
        const ushort* la = (it & 1) ? lds_a1 : lds_a0;
        const ushort* lb = (it & 1) ? lds_b1 : lds_b0;
        if (it + 1 < CIN / 32)
            stage((it + 1) * 32, (it & 1) ? lds_a0 : lds_a1,
                                 (it & 1) ? lds_b0 : lds_b1);
        bf16x8 af[4], bfv[4];
        #pragma unroll
        for (int m = 0; m < 4; ++m)
            af[m] = *(const bf16x8*)&la[(wm * 64 + m * 16 + l15) * 32 + (l4 << 3)];
        #pragma unroll
        for (int n = 0; n < 4; ++n)
            bfv[n] = *(const bf16x8*)&lb[(wn * 64 + n * 16 + l15) * 32 + (l4 << 3)];
        #pragma unroll
        for (int m = 0; m < 4; ++m)
            #pragma unroll
            for (int n = 0; n < 4; ++n)
                acc[m][n] = MFMA(af[m], bfv[n], acc[m][n]);
        __syncthreads();
    }
    // epilogue: o-block (128-aligned) sits in exactly one (head, q/k/v) chunk
    const int h = o0 / 384, which = (o0 % 384) / 128;
    const int bh = b * NH + h;
    #pragma unroll
    for (int m = 0; m < 4; ++m) {
        const int d0 = wm * 64 + m * 16 + (l4 << 2);
        float bia[4];
        #pragma unroll
        for (int r = 0; r < 4; ++r) bia[r] = bias[o0 + d0 + r];
        #pragma unroll
        for (int n = 0; n < 4; ++n) {
            const int i = i0 + wn * 64 + n * 16 + l15;
            float v0 = acc[m][n][0] + bia[0], v1 = acc[m][n][1] + bia[1];
            float v2 = acc[m][n][2] + bia[2], v3 = acc[m][n][3] + bia[3];
            if (which == 2) {                     // v: transposed store [bh][d][i]
                vtb[((size_t)bh * DK + d0 + 0) * SEQ + i] = f2bf(v0);
                vtb[((size_t)bh * DK + d0 + 1) * SEQ + i] = f2bf(v1);
                vtb[((size_t)bh * DK + d0 + 2) * SEQ + i] = f2bf(v2);
                vtb[((size_t)bh * DK + d0 + 3) * SEQ + i] = f2bf(v3);
            } else {                              // q/k: [bh][i][d], 8B packed
                ushort* dst = (which == 0) ? qb : kb;
                uint2 p; p.x = pk2(v0, v1); p.y = pk2(v2, v3);
                *(uint2*)&dst[((size_t)bh * SEQ + i) * DK + d0] = p;
            }
        }
    }
}

// ---------------------------------------------------------------------------
// k2: column-softmax stats via S^T = K * Q^T  (softmax axis i in lane dim).
// Double-buffered Q staging (prefetch t+1 before compute t).  Single fused
// stat output: cstat[j] = m_j + ln(sum_i exp(s_ij - m_j)).
// ---------------------------------------------------------------------------
__global__ __launch_bounds__(256) void stats_kernel(
    const ushort* __restrict__ qb, const ushort* __restrict__ kb,
    float* __restrict__ cstat)
{
    __shared__ __attribute__((aligned(16))) ushort lds_q0[64 * 128];
    __shared__ __attribute__((aligned(16))) ushort lds_q1[64 * 128];
    const int tid = threadIdx.x;
    const int lane = tid & 63, wv = tid >> 6;
    const int l15 = lane & 15, l4 = lane >> 4;
    const int swz = xcdswz(blockIdx.x, 512);
    const int bh = swz >> 3;
    const int j0 = (swz & 7) * 128 + wv * 32;
    const ushort* kbase = kb + (size_t)bh * SEQ * DK;
    const ushort* qbase = qb + (size_t)bh * SEQ * DK;

    auto stageQ = [&](int it, ushort* dst) {
        #pragma unroll
        for (int l = 0; l < 4; ++l) {
            int chunk = l * 256 + tid;
            int row = chunk >> 4, c = chunk & 15;
            g2l16(&qbase[(size_t)(it * 64 + row) * DK + ((c ^ (row & 7)) << 3)],
                  &dst[(size_t)(l * 256 + wv * 64) * 8]);
        }
    };

    bf16x8 kf[2][4];                      // wave's K rows [j32][128] in regs
    #pragma unroll
    for (int m = 0; m < 2; ++m)
        #pragma unroll
        for (int ks = 0; ks < 4; ++ks)
            kf[m][ks] = *(const bf16x8*)&kbase[(size_t)(j0 + m * 16 + l15) * DK
                                               + ks * 32 + (l4 << 3)];
    float mm[2][4], ss[2][4];
    #pragma unroll
    for (int m = 0; m < 2; ++m)
        #pragma unroll
        for (int r = 0; r < 4; ++r) { mm[m][r] = -1e30f; ss[m][r] = 0.0f; }

    stageQ(0, lds_q0);
    __syncthreads();
    for (int it = 0; it < SEQ / 64; ++it) {
        const ushort* lq = (it & 1) ? lds_q1 : lds_q0;
        if (it + 1 < SEQ / 64)
            stageQ(it + 1, (it & 1) ? lds_q0 : lds_q1);
        f32x4 sa0[4], sa1[4];
        __builtin_amdgcn_s_setprio(1);
        #pragma unroll
        for (int n = 0; n < 4; ++n) {
            f32x4 a0 = {}, a1 = {};
            #pragma unroll
            for (int ks = 0; ks < 4; ++ks) {
                bf16x8 bq = *(const bf16x8*)&lq[(n * 16 + l15) * 128
                                + ((((ks << 2) | l4) ^ (l15 & 7)) << 3)];
                a0 = MFMA(kf[0][ks], bq, a0);
                a1 = MFMA(kf[1][ks], bq, a1);
            }
            sa0[n] = a0; sa1[n] = a1;
        }
        __builtin_amdgcn_s_setprio(0);
        #pragma unroll
        for (int r = 0; r < 4; ++r) {
            {   // m = 0
                float v0 = sa0[0][r] * SCALE, v1 = sa0[1][r] * SCALE;
                float v2 = sa0[2][r] * SCALE, v3 = sa0[3][r] * SCALE;
                float tm = fmaxf(fmaxf(v0, v1), fmaxf(v2, v3));
                float nm = fmaxf(mm[0][r], tm);
                float s4 = __expf(v0 - nm) + __expf(v1 - nm)
                         + __expf(v2 - nm) + __expf(v3 - nm);
                ss[0][r] = ss[0][r] * __expf(mm[0][r] - nm) + s4;
                mm[0][r] = nm;
            }
            {   // m = 1
                float v0 = sa1[0][r] * SCALE, v1 = sa1[1][r] * SCALE;
                float v2 = sa1[2][r] * SCALE, v3 = sa1[3][r] * SCALE;
                float tm = fmaxf(fmaxf(v0, v1), fmaxf(v2, v3));
                float nm = fmaxf(mm[1][r], tm);
                float s4 = __expf(v0 - nm) + __expf(v1 - nm)
                         + __expf(v2 - nm) + __expf(v3 - nm);
                ss[1][r] = ss[1][r] * __expf(mm[1][r] - nm) + s4;
                mm[1][r] = nm;
            }
        }
        __syncthreads();
    }
    #pragma unroll
    for (int m = 0; m < 2; ++m)
        #pragma unroll
        for (int r = 0; r < 4; ++r) {
            float mv = mm[m][r], sv = ss[m][r];
            #pragma unroll
            for (int wmask = 1; wmask < 16; wmask <<= 1) {
                float mo = __shfl_xor(mv, wmask, 64);
                float so = __shfl_xor(sv, wmask, 64);
                float mn = fmaxf(mv, mo);
                sv = sv * __expf(mv - mn) + so * __expf(mo - mn);
                mv = mn;
            }
            if (l15 == 0) {
                int j = j0 + m * 16 + (l4 << 2) + r;
                cstat[(size_t)bh * SEQ + j] = mv + __logf(sv);
            }
        }
}

// ---------------------------------------------------------------------------
// k3: attention output.  Per i-tile(64): loop j-tiles(64):
//   stage Vt(t) ; phase A: S^T=K*Q^T, P=exp(scale*S - c_j) -> lds_p ; sync ;
//   stage K(t+1) ; phase B: O^T += V^T * P^T ; sync.
// Staging always issued BEFORE a compute phase (T3-minimum pipeline).
// ---------------------------------------------------------------------------
__global__ __launch_bounds__(256) void attn_kernel(
    const ushort* __restrict__ qb, const ushort* __restrict__ kb,
    const ushort* __restrict__ vtb, const float* __restrict__ cstat,
    ushort* __restrict__ resb)
{
    __shared__ __attribute__((aligned(16))) ushort lds_k[64 * 128];   // [j][d] swz
    __shared__ __attribute__((aligned(16))) ushort lds_vt[128 * 64];  // [d][j] swz
    __shared__ __attribute__((aligned(16))) ushort lds_p[64 * 72];    // [i][j] pad
    const int tid = threadIdx.x;
    const int lane = tid & 63, wv = tid >> 6;
    const int l15 = lane & 15, l4 = lane >> 4;
    const int wj = wv & 1, wi = wv >> 1;
    const int swz = xcdswz(blockIdx.x, 1024);
    const int bh = swz >> 4, b = bh >> 2, h = bh & 3;
    const int i0 = (swz & 15) * 64;
    const ushort* qbase = qb + (size_t)bh * SEQ * DK;
    const ushort* kbase = kb + (size_t)bh * SEQ * DK;
    const ushort* vtbase = vtb + (size_t)bh * DK * SEQ;
    const float* cbase = cstat + (size_t)bh * SEQ;

    auto stageK = [&](int j0t) {
        #pragma unroll
        for (int l = 0; l < 4; ++l) {
            int chunk = l * 256 + tid;
            int row = chunk >> 4, c = chunk & 15;
            g2l16(&kbase[(size_t)(j0t + row) * DK + ((c ^ (row & 7)) << 3)],
                  &lds_k[(size_t)(l * 256 + wv * 64) * 8]);
        }
    };
    auto stageVt = [&](int j0t) {
        #pragma unroll
        for (int l = 0; l < 4; ++l) {
            int chunk = l * 256 + tid;
            int row = chunk >> 3, c = chunk & 7;
            g2l16(&vtbase[(size_t)row * SEQ + j0t + ((c ^ (row & 7)) << 3)],
                  &lds_vt[(size_t)(l * 256 + wv * 64) * 8]);
        }
    };

    bf16x8 qf[2][4];                      // wave's Q rows [i32][128] in regs
    #pragma unroll
    for (int n = 0; n < 2; ++n)
        #pragma unroll
        for (int ks = 0; ks < 4; ++ks)
            qf[n][ks] = *(const bf16x8*)&qbase[(size_t)(i0 + wi * 32 + n * 16 + l15) * DK
                                               + ks * 32 + (l4 << 3)];
    f32x4 oacc[2][4] = {};

    stageK(0);
    __syncthreads();
    for (int jt = 0; jt < SEQ / 64; ++jt) {
        const int j0 = jt * 64;
        stageVt(j0);                               // needed only in phase B
        float4 cs0 = *(const float4*)&cbase[j0 + wj * 32 + (l4 << 2)];
        float4 cs1 = *(const float4*)&cbase[j0 + wj * 32 + 16 + (l4 << 2)];
        float cj[2][4] = {{cs0.x, cs0.y, cs0.z, cs0.w},
                          {cs1.x, cs1.y, cs1.z, cs1.w}};
        // ---- phase A (reads lds_k) ----
        bf16x8 af[2][4];
        #pragma unroll
        for (int m = 0; m < 2; ++m)
            #pragma unroll
            for (int ks = 0; ks < 4; ++ks)
                af[m][ks] = *(const bf16x8*)&lds_k[(wj * 32 + m * 16 + l15) * 128
                                + ((((ks << 2) | l4) ^ (l15 & 7)) << 3)];
        __builtin_amdgcn_s_setprio(1);
        #pragma unroll
        for (int m = 0; m < 2; ++m)
            #pragma unroll
            for (int n = 0; n < 2; ++n) {
                f32x4 s = {};
                #pragma unroll
                for (int ks = 0; ks < 4; ++ks)
                    s = MFMA(af[m][ks], qf[n][ks], s);
                const int i = wi * 32 + n * 16 + l15;
                float p0 = __expf(s[0] * SCALE - cj[m][0]);
                float p1 = __expf(s[1] * SCALE - cj[m][1]);
                float p2 = __expf(s[2] * SCALE - cj[m][2]);
                float p3 = __expf(s[3] * SCALE - cj[m][3]);
                uint2 pp; pp.x = pk2(p0, p1); pp.y = pk2(p2, p3);
                *(uint2*)&lds_p[i * 72 + wj * 32 + m * 16 + (l4 << 2)] = pp;
            }
        __builtin_amdgcn_s_setprio(0);
        __syncthreads();                           // Vt(t) ready; lds_k free; P visible
        if (jt + 1 < SEQ / 64) stageK(j0 + 64);    // prefetch under phase B
        // ---- phase B (reads lds_vt + lds_p) ----
        __builtin_amdgcn_s_setprio(1);
        #pragma unroll
        for (int ks = 0; ks < 2; ++ks) {
            bf16x8 va0 = *(const bf16x8*)&lds_vt[(wv * 32 + l15) * 64
                            + ((((ks << 2) | l4) ^ (l15 & 7)) << 3)];
            bf16x8 va1 = *(const bf16x8*)&lds_vt[(wv * 32 + 16 + l15) * 64
                            + ((((ks << 2) | l4) ^ (l15 & 7)) << 3)];
            #pragma unroll
            for (int n = 0; n < 4; ++n) {
                bf16x8 pb = *(const bf16x8*)&lds_p[(n * 16 + l15) * 72
                                + ks * 32 + (l4 << 3)];
                oacc[0][n] = MFMA(va0, pb, oacc[0][n]);
                oacc[1][n] = MFMA(va1, pb, oacc[1][n]);
            }
        }
        __builtin_amdgcn_s_setprio(0);
        __syncthreads();                           // K(t+1) ready; lds_vt/lds_p free
    }
    // epilogue: O^T[d][i] -> resb [b][i][h*128 + d]
    #pragma unroll
    for (int m = 0; m < 2; ++m)
        #pragma unroll
        for (int n = 0; n < 4; ++n) {
            const int i = i0 + n * 16 + l15;
            const int d = wv * 32 + m * 16 + (l4 << 2);
            uint2 p;
            p.x = pk2(oacc[m][n][0], oacc[m][n][1]);
            p.y = pk2(oacc[m][n][2], oacc[m][n][3]);
            *(uint2*)&resb[((size_t)b * SEQ + i) * (NH * DK) + h * DK + d] = p;
        }
}

// ---------------------------------------------------------------------------
// k4: out projection + bias + residual (double-buffered prefetch).
//   out[b][c][i] = sum_k Woutbf[c][k]*res[i][k] + bout[c] + x[b][c][i]
// ---------------------------------------------------------------------------
__global__ __launch_bounds__(256) void outproj_kernel(
    const ushort* __restrict__ resb, const ushort* __restrict__ woutbf,
    const float* __restrict__ bout, const float* __restrict__ x,
    float* __restrict__ out)
{
    __shared__ __attribute__((aligned(16))) ushort lds_a0[128 * 32];
    __shared__ __attribute__((aligned(16))) ushort lds_a1[128 * 32];
    __shared__ __attribute__((aligned(16))) ushort lds_b0[128 * 32];
    __shared__ __attribute__((aligned(16))) ushort lds_b1[128 * 32];
    const int tid = threadIdx.x;
    const int lane = tid & 63, wv = tid >> 6;
    const int l15 = lane & 15, l4 = lane >> 4;
    const int wm = wv >> 1, wn = wv & 1;
    const int swz = xcdswz(blockIdx.x, 512);
    const int i0 = (swz & 7) * 128;
    const int c0 = ((swz >> 3) & 3) * 128;
    const int b  = swz >> 5;

    auto stage = [&](int k0, ushort* la, ushort* lb) {
        #pragma unroll
        for (int l = 0; l < 2; ++l) {
            int chunk = l * 256 + tid;
            int row = chunk >> 2, c = chunk & 3;
            g2l16(&woutbf[(size_t)(c0 + row) * (NH * DK) + k0 + (c << 3)],
                  &la[(size_t)(l * 256 + wv * 64) * 8]);
        }
        #pragma unroll
        for (int l = 0; l < 2; ++l) {
            int chunk = l * 256 + tid;
            int row = chunk >> 2, c = chunk & 3;
            g2l16(&resb[((size_t)b * SEQ + i0 + row) * (NH * DK) + k0 + (c << 3)],
                  &lb[(size_t)(l * 256 + wv * 64) * 8]);
        }
    };

    f32x4 acc[4][4] = {};
    stage(0, lds_a0, lds_b0);
    __syncthreads();
    for (int it = 0; it < (NH * DK) / 32; ++it) {
        const ushort* la = (it & 1) ? lds_a1 : lds_a0;
        const ushort* lb = (it & 1) ? lds_b1 : lds_b0;
        if (it + 1 < (NH * DK) / 32)
            stage((it + 1) * 32, (it & 1) ? lds_a0 : lds_a1,
                                 (it & 1) ? lds_b0 : lds_b1);
        bf16x8 af[4], bfv[4];
        #pragma unroll
        for (int m = 0; m < 4; ++m)
            af[m] = *(const bf16x8*)&la[(wm * 64 + m * 16 + l15) * 32 + (l4 << 3)];
        #pragma unroll
        for (int n = 0; n < 4; ++n)
            bfv[n] = *(const bf16x8*)&lb[(wn * 64 + n * 16 + l15) * 32 + (l4 << 3)];
        #pragma unroll
        for (int m = 0; m < 4; ++m)
            #pragma unroll
            for (int n = 0; n < 4; ++n)
                acc[m][n] = MFMA(af[m], bfv[n], acc[m][n]);
        __syncthreads();
    }
    #pragma unroll
    for (int m = 0; m < 4; ++m) {
        const int cb = c0 + wm * 64 + m * 16 + (l4 << 2);
        float bia[4];
        #pragma unroll
        for (int r = 0; r < 4; ++r) bia[r] = bout[cb + r];
        #pragma unroll
        for (int n = 0; n < 4; ++n) {
            const int i = i0 + wn * 64 + n * 16 + l15;
            #pragma unroll
            for (int r = 0; r < 4; ++r) {
                size_t off = ((size_t)b * CIN + cb + r) * SEQ + i;
                out[off] = acc[m][n][r] + bia[r] + x[off];
            }
        }
    }
}

// ---------------------------------------------------------------------------
extern "C" void kernel_launch(void* const* d_in, const int* in_sizes, int n_in,
                              void* d_out, int out_size, void* d_ws, size_t ws_size,
                              hipStream_t stream) {
    const float* x      = (const float*)d_in[0];
    const float* w_proj = (const float*)d_in[1];
    const float* b_proj = (const float*)d_in[2];
    const float* w_out  = (const float*)d_in[3];
    const float* b_out  = (const float*)d_in[4];
    // n_heads (d_in[5]) hardcoded = 4

    const size_t xtE = (size_t)B_ * SEQ * CIN;        // bf16 elements
    const size_t qkE = (size_t)B_ * NH * SEQ * DK;    // bf16 elements
    ushort* xt    = (ushort*)d_ws;
    ushort* qb    = xt + xtE;
    ushort* kb    = qb + qkE;
    ushort* vtb   = kb + qkE;
    float*  cstat = (float*)(vtb + qkE);
    ushort* resb  = (ushort*)(cstat + 2 * (size_t)B_ * NH * SEQ);
    ushort* wobf  = resb + (size_t)B_ * SEQ * (NH * DK);
    // wpbf aliases resb: wpbf live only prep->qkv; resb written first in attn.
    ushort* wpbf  = resb;
    float*  out   = (float*)d_out;

    transpose_cast_kernel<<<dim3(SEQ / 64, CIN / 64, B_), 256, 0, stream>>>(x, xt);
    cast_kernel<<<dim3(768), 256, 0, stream>>>(w_proj, wpbf, 196608);  // 1536*512/4
    cast_kernel<<<dim3(256), 256, 0, stream>>>(w_out, wobf, 65536);    // 512*512/4
    qkv_kernel<<<dim3(1536), 256, 0, stream>>>(wpbf, b_proj, xt, qb, kb, vtb);
    stats_kernel<<<dim3(512), 256, 0, stream>>>(qb, kb, cstat);
    attn_kernel<<<dim3(1024), 256, 0, stream>>>(qb, kb, vtb, cstat, resb);
    outproj_kernel<<<dim3(512), 256, 0, stream>>>(resb, wobf, b_out, x, out);
}